// Round 1
// baseline (374.708 us; speedup 1.0000x reference)
//
#include <hip/hip_runtime.h>
#include <stdint.h>
#include <stddef.h>

typedef int v4i __attribute__((ext_vector_type(4)));

#define GELU_A   (-0.2888f)
#define GELU_B   (-1.769f)
#define INV_SQRT2 0.70710678118654752440f

// ---- order-preserving float<->uint encoding for atomic min/max ----
__device__ __forceinline__ unsigned enc_f(float f){
  unsigned u = __float_as_uint(f);
  return (u & 0x80000000u) ? ~u : (u | 0x80000000u);
}
__device__ __forceinline__ float dec_f(unsigned e){
  unsigned u = (e & 0x80000000u) ? (e & 0x7FFFFFFFu) : ~e;
  return __uint_as_float(u);
}

__device__ __forceinline__ float int_gelu_f(float x){
  float t = x * INV_SQRT2;
  float at = fminf(fabsf(t), 1.769f);
  float u = at + GELU_B;                 // in [-1.769, 0]
  float p = GELU_A * (u * u) + 1.0f;
  float L = (t > 0.0f) ? p : ((t < 0.0f) ? -p : 0.0f);
  return x * 0.5f * (1.0f + L);
}

// scalar slots: 0 enc(xmin), 1 enc(xmax), 2 bits(absmax w1), 3 bits(absmax w2),
//               4 enc(gmin), 5 enc(gmax)
__global__ void init_scalars(unsigned* sc){
  if (threadIdx.x == 0){
    sc[0] = 0xFFFFFFFFu;
    sc[1] = 0u;
    sc[2] = 0u;
    sc[3] = 0u;
    sc[4] = 0xFFFFFFFFu;
    sc[5] = 0u;
  }
}

// blocks [0,512): x min/max; [512,640): absmax w1 -> slot2; [640,768): absmax w2 -> slot3
__global__ __launch_bounds__(256) void reduce_stats(
    const float4* __restrict__ x, int nx4,
    const float4* __restrict__ w1, int n14,
    const float4* __restrict__ w2, int n24,
    unsigned* __restrict__ sc)
{
  __shared__ float ra[256], rb[256];
  const int tid = threadIdx.x;
  const int b = blockIdx.x;
  if (b < 512){
    float lmin = 3.4e38f, lmax = -3.4e38f;
    for (long i = (long)b * 256 + tid; i < nx4; i += 512L * 256L){
      float4 v = x[i];
      lmin = fminf(lmin, fminf(fminf(v.x, v.y), fminf(v.z, v.w)));
      lmax = fmaxf(lmax, fmaxf(fmaxf(v.x, v.y), fmaxf(v.z, v.w)));
    }
    ra[tid] = lmin; rb[tid] = lmax;
    __syncthreads();
    for (int s = 128; s > 0; s >>= 1){
      if (tid < s){ ra[tid] = fminf(ra[tid], ra[tid + s]); rb[tid] = fmaxf(rb[tid], rb[tid + s]); }
      __syncthreads();
    }
    if (tid == 0){
      atomicMin(&sc[0], enc_f(ra[0]));
      atomicMax(&sc[1], enc_f(rb[0]));
    }
  } else {
    const float4* w; int n4; int slot; int bl;
    if (b < 640){ w = w1; n4 = n14; slot = 2; bl = b - 512; }
    else        { w = w2; n4 = n24; slot = 3; bl = b - 640; }
    float la = 0.0f;
    for (long i = (long)bl * 256 + tid; i < n4; i += 128L * 256L){
      float4 v = w[i];
      la = fmaxf(la, fmaxf(fmaxf(fabsf(v.x), fabsf(v.y)), fmaxf(fabsf(v.z), fabsf(v.w))));
    }
    ra[tid] = la;
    __syncthreads();
    for (int s = 128; s > 0; s >>= 1){
      if (tid < s) ra[tid] = fmaxf(ra[tid], ra[tid + s]);
      __syncthreads();
    }
    if (tid == 0) atomicMax(&sc[slot], __float_as_uint(ra[0]));
  }
}

// per-tensor asymmetric uint8 fake-quant of activations, stored as (q-128) int8
__global__ __launch_bounds__(256) void quant_act(
    const float4* __restrict__ in, unsigned* __restrict__ out, long n4,
    const unsigned* __restrict__ sc, int slot)
{
  const float vmin = dec_f(sc[slot]);
  const float vmax = dec_f(sc[slot + 1]);
  const float s  = fmaxf(vmax - vmin, 1e-8f) / 255.0f;
  const float zp = rintf(-vmin / s);
  const long stride = (long)gridDim.x * blockDim.x;
  for (long i = (long)blockIdx.x * blockDim.x + threadIdx.x; i < n4; i += stride){
    float4 v = in[i];
    int q0 = (int)fminf(fmaxf(rintf(v.x / s) + zp, 0.0f), 255.0f) - 128;
    int q1 = (int)fminf(fmaxf(rintf(v.y / s) + zp, 0.0f), 255.0f) - 128;
    int q2 = (int)fminf(fmaxf(rintf(v.z / s) + zp, 0.0f), 255.0f) - 128;
    int q3 = (int)fminf(fmaxf(rintf(v.w / s) + zp, 0.0f), 255.0f) - 128;
    out[i] = ((unsigned)(q0 & 255)) | ((unsigned)(q1 & 255) << 8) |
             ((unsigned)(q2 & 255) << 16) | ((unsigned)(q3 & 255) << 24);
  }
}

// per-tensor symmetric int8 weight fake-quant; one block per row; also row sums
__global__ __launch_bounds__(256) void quant_w(
    const float* __restrict__ w1, const float* __restrict__ w2,
    int8_t* __restrict__ qw1, int8_t* __restrict__ qw2,
    int* __restrict__ rs1, int* __restrict__ rs2,
    const unsigned* __restrict__ sc, int n1, int k1, int k2)
{
  __shared__ int red[256];
  const int b = blockIdx.x, tid = threadIdx.x;
  const float* w; int8_t* q; int* rs; int K; int n; float s;
  if (b < n1){ w = w1; q = qw1; rs = rs1; K = k1; n = b;
               s = fmaxf(__uint_as_float(sc[2]), 1e-8f) / 127.0f; }
  else       { w = w2; q = qw2; rs = rs2; K = k2; n = b - n1;
               s = fmaxf(__uint_as_float(sc[3]), 1e-8f) / 127.0f; }
  int sum = 0;
  for (int k = tid; k < K; k += 256){
    float v = w[(size_t)n * K + k];
    float qf = fminf(fmaxf(rintf(v / s), -128.0f), 127.0f);
    int qi = (int)qf;
    q[(size_t)n * K + k] = (int8_t)qi;
    sum += qi;
  }
  red[tid] = sum;
  __syncthreads();
  for (int st = 128; st > 0; st >>= 1){
    if (tid < st) red[tid] += red[tid + st];
    __syncthreads();
  }
  if (tid == 0) rs[n] = red[0];
}

// MODE 0: h->gelu-> g min/max atomics only (no store)
// MODE 2: h->gelu-> quantize with g stats -> store int8 (q-128)
// MODE 1: h + bias -> store fp32 out
// A: [M,K] int8 (a=q-128), Bm: [N,K] int8, tile 128x128xBK64,
// 4 waves, each 64x64 via 4x4 of mfma_i32_16x16x64_i8.
template<int MODE>
__global__ __launch_bounds__(256) void gemm_i8(
    const int8_t* __restrict__ A, const int8_t* __restrict__ Bm,
    const int* __restrict__ rowsum, const float* __restrict__ bias,
    void* __restrict__ Cout, int M, int N, int K,
    unsigned* __restrict__ sc)
{
  __shared__ __align__(16) int8_t ldsA[128 * 80];  // row stride 80 = 64B data + 16B pad (bank-conflict-free frags)
  __shared__ __align__(16) int8_t ldsB[128 * 80];
  __shared__ float redA[256];
  __shared__ float redB[256];

  const int tid  = threadIdx.x;
  const int n0   = blockIdx.x * 128;
  const int m0   = blockIdx.y * 128;
  const int lane = tid & 63;
  const int wave = tid >> 6;
  const int m16  = lane & 15;
  const int quad = lane >> 4;
  const int wm   = (wave & 1) * 64;
  const int wn   = (wave >> 1) * 64;

  // staging: 512 16B-chunks per tile; thread handles chunks tid and tid+256
  const int sr  = tid >> 2;   // row 0..63
  const int scn = tid & 3;    // 16B chunk in 64B row
  int mg0 = m0 + sr;      if (mg0 >= M) mg0 = M - 1;
  int mg1 = m0 + sr + 64; if (mg1 >= M) mg1 = M - 1;
  const size_t aoff0 = (size_t)mg0 * K + scn * 16;
  const size_t aoff1 = (size_t)mg1 * K + scn * 16;
  const size_t boff0 = (size_t)(n0 + sr) * K + scn * 16;
  const size_t boff1 = (size_t)(n0 + sr + 64) * K + scn * 16;
  int8_t* wA0 = ldsA + sr * 80 + scn * 16;
  int8_t* wA1 = ldsA + (sr + 64) * 80 + scn * 16;
  int8_t* wB0 = ldsB + sr * 80 + scn * 16;
  int8_t* wB1 = ldsB + (sr + 64) * 80 + scn * 16;

  v4i acc[4][4] = {};

  for (int k0 = 0; k0 < K; k0 += 64){
    uint4 a0 = *(const uint4*)(A + aoff0 + k0);
    uint4 a1 = *(const uint4*)(A + aoff1 + k0);
    uint4 b0 = *(const uint4*)(Bm + boff0 + k0);
    uint4 b1 = *(const uint4*)(Bm + boff1 + k0);
    __syncthreads();
    *(uint4*)wA0 = a0; *(uint4*)wA1 = a1;
    *(uint4*)wB0 = b0; *(uint4*)wB1 = b1;
    __syncthreads();
    v4i af[4], bf[4];
#pragma unroll
    for (int i = 0; i < 4; i++){
      af[i] = *(const v4i*)(ldsA + (wm + i * 16 + m16) * 80 + quad * 16);
      bf[i] = *(const v4i*)(ldsB + (wn + i * 16 + m16) * 80 + quad * 16);
    }
#pragma unroll
    for (int i = 0; i < 4; i++)
#pragma unroll
      for (int j = 0; j < 4; j++)
        acc[i][j] = __builtin_amdgcn_mfma_i32_16x16x64_i8(af[i], bf[j], acc[i][j], 0, 0, 0);
  }

  // epilogue scalars
  float s_h, off_h;
  if constexpr (MODE == 1){
    float gmin = dec_f(sc[4]), gmax = dec_f(sc[5]);
    float sg = fmaxf(gmax - gmin, 1e-8f) / 255.0f;
    float zp = rintf(-gmin / sg);
    float sw = fmaxf(__uint_as_float(sc[3]), 1e-8f) / 127.0f;
    s_h = sg * sw; off_h = 128.0f - zp;
  } else {
    float xmin = dec_f(sc[0]), xmax = dec_f(sc[1]);
    float sx = fmaxf(xmax - xmin, 1e-8f) / 255.0f;
    float zp = rintf(-xmin / sx);
    float sw = fmaxf(__uint_as_float(sc[2]), 1e-8f) / 127.0f;
    s_h = sx * sw; off_h = 128.0f - zp;
  }
  float qs = 1.0f, qzp = 0.0f;
  if constexpr (MODE == 2){
    float gmin = dec_f(sc[4]), gmax = dec_f(sc[5]);
    qs = fmaxf(gmax - gmin, 1e-8f) / 255.0f;
    qzp = rintf(-gmin / qs);
  }

  float lmin = 3.4e38f, lmax = -3.4e38f;
#pragma unroll
  for (int j = 0; j < 4; j++){
    const int n = n0 + wn + j * 16 + m16;
    const float rsv = off_h * (float)rowsum[n];
    const float bv = bias[n];
#pragma unroll
    for (int i = 0; i < 4; i++){
      const int mbase = m0 + wm + i * 16 + quad * 4;
#pragma unroll
      for (int r = 0; r < 4; r++){
        const int m = mbase + r;
        if (m < M){
          float h = s_h * ((float)acc[i][j][r] + rsv) + bv;
          if constexpr (MODE == 0){
            float gv = int_gelu_f(h);
            lmin = fminf(lmin, gv); lmax = fmaxf(lmax, gv);
          } else if constexpr (MODE == 2){
            float gv = int_gelu_f(h);
            float qf = fminf(fmaxf(rintf(gv / qs) + qzp, 0.0f), 255.0f);
            ((int8_t*)Cout)[(size_t)m * N + n] = (int8_t)((int)qf - 128);
          } else {
            ((float*)Cout)[(size_t)m * N + n] = h;
          }
        }
      }
    }
  }

  if constexpr (MODE == 0){
    redA[tid] = lmin; redB[tid] = lmax;
    __syncthreads();
    for (int st = 128; st > 0; st >>= 1){
      if (tid < st){
        redA[tid] = fminf(redA[tid], redA[tid + st]);
        redB[tid] = fmaxf(redB[tid], redB[tid + st]);
      }
      __syncthreads();
    }
    if (tid == 0){
      atomicMin(&sc[4], enc_f(redA[0]));
      atomicMax(&sc[5], enc_f(redB[0]));
    }
  }
}

extern "C" void kernel_launch(void* const* d_in, const int* in_sizes, int n_in,
                              void* d_out, int out_size, void* d_ws, size_t ws_size,
                              hipStream_t stream)
{
  const float* x  = (const float*)d_in[0];
  const float* w1 = (const float*)d_in[1];
  const float* b1 = (const float*)d_in[2];
  const float* w2 = (const float*)d_in[3];
  const float* b2 = (const float*)d_in[4];
  float* out = (float*)d_out;

  const int H = in_sizes[2];            // 3072
  const int D = in_sizes[4];            // 768
  const int M = in_sizes[0] / D;        // 12608

  char* ws = (char*)d_ws;
  unsigned* sc = (unsigned*)ws;
  size_t off = 256;
  int8_t* qx  = (int8_t*)(ws + off); off += (size_t)M * D;   // 9.68 MB
  int8_t* qw1 = (int8_t*)(ws + off); off += (size_t)H * D;   // 2.36 MB
  int8_t* qw2 = (int8_t*)(ws + off); off += (size_t)D * H;   // 2.36 MB
  int* rs1 = (int*)(ws + off); off += (size_t)H * 4;
  int* rs2 = (int*)(ws + off); off += 4096;
  int8_t* qg  = (int8_t*)(ws + off); off += (size_t)M * H;   // 38.7 MB
  (void)ws_size; (void)n_in; (void)out_size;

  init_scalars<<<dim3(1), dim3(64), 0, stream>>>(sc);

  reduce_stats<<<dim3(768), dim3(256), 0, stream>>>(
      (const float4*)x, M * D / 4,
      (const float4*)w1, H * D / 4,
      (const float4*)w2, D * H / 4, sc);

  quant_act<<<dim3(1024), dim3(256), 0, stream>>>(
      (const float4*)x, (unsigned*)qx, (long)M * D / 4, sc, 0);

  quant_w<<<dim3(H + D), dim3(256), 0, stream>>>(
      w1, w2, qw1, qw2, rs1, rs2, sc, H, D, H);

  // GEMM1 pass A: g min/max only
  gemm_i8<0><<<dim3(H / 128, (M + 127) / 128), dim3(256), 0, stream>>>(
      qx, qw1, rs1, b1, nullptr, M, H, D, sc);

  // GEMM1 pass B: recompute, quantize g -> qg (int8, q-128)
  gemm_i8<2><<<dim3(H / 128, (M + 127) / 128), dim3(256), 0, stream>>>(
      qx, qw1, rs1, b1, qg, M, H, D, sc);

  // GEMM2: out = qg @ qw2^T + b2
  gemm_i8<1><<<dim3(D / 128, (M + 127) / 128), dim3(256), 0, stream>>>(
      qg, qw2, rs2, b2, out, M, D, H, sc);
}